// Round 1
// baseline (82.356 us; speedup 1.0000x reference)
//
#include <hip/hip_runtime.h>
#include <hip/hip_bf16.h>

// Adaptive avg pool: in (16,224,224,128) f32 NHWC -> out (16,7,7,128) f32.
// 224/7 = 32 exactly, so every bin is a uniform 32x32 window (1024 elems).
//
// One 256-thread block per output region (b,i,j): 16*7*7 = 784 blocks.
// Each region row = 32 w-positions * 128 ch = 4096 contiguous floats (16 KB).
// Thread t accumulates float4 at element offsets k*1024 + t*4 (k=0..3) per
// row; since 1024 % 128 == 0, thread t always owns channels (t%32)*4..+3.
// LDS reduce 8 partials/channel-group, then coalesced float4 store.

#define REGIONS (16 * 7 * 7)

__global__ __launch_bounds__(256) void AdaptivePooling2D_48146583388556_kernel(
    const float* __restrict__ x, float* __restrict__ out) {
    const int bid = blockIdx.x;          // [0, 784)
    const int t   = threadIdx.x;         // [0, 256)

    const int b   = bid / 49;
    const int rem = bid - b * 49;
    const int i   = rem / 7;
    const int j   = rem - i * 7;

    // Base of region (b, i*32, j*32, 0) in float4 units.
    const size_t base_f = ((size_t)(b * 224 + i * 32) * 224 + (size_t)j * 32) * 128;
    const float4* base = reinterpret_cast<const float4*>(x + base_f);
    const size_t row_stride4 = (size_t)224 * 128 / 4;  // 7168 float4 per H-row

    float4 acc = make_float4(0.f, 0.f, 0.f, 0.f);
    #pragma unroll 4
    for (int h = 0; h < 32; ++h) {
        const float4* row = base + (size_t)h * row_stride4;
        #pragma unroll
        for (int k = 0; k < 4; ++k) {
            float4 v = row[k * 256 + t];   // coalesced: consecutive t -> consecutive 16B
            acc.x += v.x; acc.y += v.y; acc.z += v.z; acc.w += v.w;
        }
    }

    __shared__ float4 sm[256];
    sm[t] = acc;
    __syncthreads();

    if (t < 32) {
        float4 s = sm[t];
        #pragma unroll
        for (int k = 1; k < 8; ++k) {
            float4 v = sm[t + 32 * k];
            s.x += v.x; s.y += v.y; s.z += v.z; s.w += v.w;
        }
        const float scale = 1.0f / 1024.0f;
        float4 o = make_float4(s.x * scale, s.y * scale, s.z * scale, s.w * scale);
        // out[bid*128 + t*4 .. +3]; bid == ((b*7+i)*7+j)
        reinterpret_cast<float4*>(out + (size_t)bid * 128)[t] = o;
    }
}

extern "C" void kernel_launch(void* const* d_in, const int* in_sizes, int n_in,
                              void* d_out, int out_size, void* d_ws, size_t ws_size,
                              hipStream_t stream) {
    const float* x  = (const float*)d_in[0];
    float* out      = (float*)d_out;
    AdaptivePooling2D_48146583388556_kernel<<<REGIONS, 256, 0, stream>>>(x, out);
}

// Round 2
// 79.549 us; speedup vs baseline: 1.0353x; 1.0353x over previous
//
#include <hip/hip_runtime.h>
#include <hip/hip_bf16.h>

// Adaptive avg pool: in (16,224,224,128) f32 NHWC -> out (16,7,7,128) f32.
// Bins are uniform 32x32 windows (224 = 7*32).
//
// Round-1 analysis: one block per region (784 blocks) = 3.06 blocks/CU ->
// 16 CUs get 4 blocks while 240 get 3 -> ~77% load balance, matching the
// measured 79%-of-achievable BW. Fix: finer granularity.
//
// Pass 1: each region split into CHUNKS row-groups (CHUNKS=8 -> 6272 blocks,
//         ~24.5/CU, tail ~4%). Block reduces 4 rows (64 KB) to a 128-float
//         partial in d_ws (deterministic, no atomics).
// Pass 2: 392 blocks x 256 threads; each thread sums CHUNKS partials for one
//         output element and scales by 1/1024. Extra traffic ~6.4 MB (1.6%).

#define REGIONS (16 * 7 * 7)   // 784
#define OUT_ELEMS (REGIONS * 128)  // 100352 = 392 * 256

template <int CHUNKS>
__global__ __launch_bounds__(256) void pool_partial(const float* __restrict__ x,
                                                    float* __restrict__ ws) {
    constexpr int ROWS = 32 / CHUNKS;
    const int bid = blockIdx.x;           // [0, 784*CHUNKS)
    const int t   = threadIdx.x;          // [0, 256)

    const int region = bid / CHUNKS;
    const int chunk  = bid - region * CHUNKS;
    const int b   = region / 49;
    const int rem = region - b * 49;
    const int i   = rem / 7;
    const int j   = rem - i * 7;

    // Base of (b, i*32 + chunk*ROWS, j*32, 0), in float4 units.
    const size_t base_f =
        ((size_t)(b * 224 + i * 32 + chunk * ROWS) * 224 + (size_t)j * 32) * 128;
    const float4* base = reinterpret_cast<const float4*>(x + base_f);
    const size_t row_stride4 = (size_t)224 * 128 / 4;  // 7168 float4 per H-row

    float4 acc = make_float4(0.f, 0.f, 0.f, 0.f);
    #pragma unroll
    for (int h = 0; h < ROWS; ++h) {
        const float4* row = base + (size_t)h * row_stride4;
        #pragma unroll
        for (int k = 0; k < 4; ++k) {
            float4 v = row[k * 256 + t];  // coalesced 16B/lane
            acc.x += v.x; acc.y += v.y; acc.z += v.z; acc.w += v.w;
        }
    }

    __shared__ float4 sm[256];
    sm[t] = acc;
    __syncthreads();

    if (t < 32) {
        float4 s = sm[t];
        #pragma unroll
        for (int k = 1; k < 8; ++k) {
            float4 v = sm[t + 32 * k];
            s.x += v.x; s.y += v.y; s.z += v.z; s.w += v.w;
        }
        reinterpret_cast<float4*>(ws + (size_t)bid * 128)[t] = s;
    }
}

template <int CHUNKS>
__global__ __launch_bounds__(256) void pool_reduce(const float* __restrict__ ws,
                                                   float* __restrict__ out) {
    const int e = blockIdx.x * 256 + threadIdx.x;  // [0, 100352)
    const int r  = e >> 7;       // region
    const int ch = e & 127;      // channel
    float s = 0.f;
    #pragma unroll
    for (int c = 0; c < CHUNKS; ++c)
        s += ws[(size_t)(r * CHUNKS + c) * 128 + ch];
    out[e] = s * (1.0f / 1024.0f);
}

// Round-0 fallback (one block per region) if ws is too small.
__global__ __launch_bounds__(256) void pool_direct(const float* __restrict__ x,
                                                   float* __restrict__ out) {
    const int bid = blockIdx.x;
    const int t   = threadIdx.x;
    const int b   = bid / 49;
    const int rem = bid - b * 49;
    const int i   = rem / 7;
    const int j   = rem - i * 7;
    const size_t base_f = ((size_t)(b * 224 + i * 32) * 224 + (size_t)j * 32) * 128;
    const float4* base = reinterpret_cast<const float4*>(x + base_f);
    const size_t row_stride4 = (size_t)224 * 128 / 4;
    float4 acc = make_float4(0.f, 0.f, 0.f, 0.f);
    #pragma unroll 4
    for (int h = 0; h < 32; ++h) {
        const float4* row = base + (size_t)h * row_stride4;
        #pragma unroll
        for (int k = 0; k < 4; ++k) {
            float4 v = row[k * 256 + t];
            acc.x += v.x; acc.y += v.y; acc.z += v.z; acc.w += v.w;
        }
    }
    __shared__ float4 sm[256];
    sm[t] = acc;
    __syncthreads();
    if (t < 32) {
        float4 s = sm[t];
        #pragma unroll
        for (int k = 1; k < 8; ++k) {
            float4 v = sm[t + 32 * k];
            s.x += v.x; s.y += v.y; s.z += v.z; s.w += v.w;
        }
        const float scale = 1.0f / 1024.0f;
        float4 o = make_float4(s.x * scale, s.y * scale, s.z * scale, s.w * scale);
        reinterpret_cast<float4*>(out + (size_t)bid * 128)[t] = o;
    }
}

extern "C" void kernel_launch(void* const* d_in, const int* in_sizes, int n_in,
                              void* d_out, int out_size, void* d_ws, size_t ws_size,
                              hipStream_t stream) {
    const float* x = (const float*)d_in[0];
    float* out     = (float*)d_out;
    float* ws      = (float*)d_ws;

    constexpr size_t need8 = (size_t)REGIONS * 8 * 128 * sizeof(float);  // 3.2 MB
    constexpr size_t need4 = (size_t)REGIONS * 4 * 128 * sizeof(float);  // 1.6 MB

    if (ws_size >= need8) {
        pool_partial<8><<<REGIONS * 8, 256, 0, stream>>>(x, ws);
        pool_reduce<8><<<OUT_ELEMS / 256, 256, 0, stream>>>(ws, out);
    } else if (ws_size >= need4) {
        pool_partial<4><<<REGIONS * 4, 256, 0, stream>>>(x, ws);
        pool_reduce<4><<<OUT_ELEMS / 256, 256, 0, stream>>>(ws, out);
    } else {
        pool_direct<<<REGIONS, 256, 0, stream>>>(x, out);
    }
}